// Round 2
// baseline (629.172 us; speedup 1.0000x reference)
//
#include <hip/hip_runtime.h>
#include <hip/hip_bf16.h>

#define S_ 4096
#define D_ 256
#define B_ 4

static constexpr float INV_SCALE = 0.08838834764831844f; // 1/sqrt(128)

typedef __bf16 bf16x8 __attribute__((ext_vector_type(8)));
typedef float f32x4 __attribute__((ext_vector_type(4)));

// byte offset into a [row][64 bf16] LDS tile, XOR-swizzled (G4: breaks the
// 128B-row-stride 32-bank alias on ds_read_b128)
__device__ __forceinline__ int swz(int row, int kbyte) {
    return (row * 128 + kbyte) ^ ((row & 7) << 4);
}

__device__ __forceinline__ uint2 pack4(float4 f) {
    union { __bf16 h[4]; uint2 u; } r;
    r.h[0] = (__bf16)f.x; r.h[1] = (__bf16)f.y;
    r.h[2] = (__bf16)f.z; r.h[3] = (__bf16)f.w;
    return r.u;
}

// ---------------------------------------------------------------------------
// K1: raw scores = Q . K^T   (scale applied later in softmax)
// tile 128x128, BK=64, 4 waves in 2x2, each wave 64x64 (4x4 fragments)
// ---------------------------------------------------------------------------
__global__ __launch_bounds__(256) void k_qk(const float* __restrict__ Q,
                                            const float* __restrict__ Km,
                                            float* __restrict__ Wt) {
    __shared__ alignas(16) unsigned short Qs[128 * 64];
    __shared__ alignas(16) unsigned short Ks[128 * 64];
    const int t = threadIdx.x;
    const int lane = t & 63;
    const int wv = t >> 6;
    const int wm = wv >> 1, wn = wv & 1;
    const int mb = blockIdx.x * 128, nb = blockIdx.y * 128;
    const int b = blockIdx.z;
    const float* Qb = Q + (size_t)b * S_ * D_;
    const float* Kb = Km + (size_t)b * S_ * D_;

    f32x4 acc[4][4];
#pragma unroll
    for (int i = 0; i < 4; i++)
#pragma unroll
        for (int j = 0; j < 4; j++) acc[i][j] = f32x4{0.f, 0.f, 0.f, 0.f};

    const int srow = t >> 4;        // 0..15
    const int scol = (t & 15) * 4;  // float col within 64-wide k slab

    for (int kb = 0; kb < D_; kb += 64) {
        float4 fq[8], fk[8];
#pragma unroll
        for (int p = 0; p < 8; p++) {
            int r = srow + p * 16;
            fq[p] = *reinterpret_cast<const float4*>(Qb + (size_t)(mb + r) * D_ + kb + scol);
            fk[p] = *reinterpret_cast<const float4*>(Kb + (size_t)(nb + r) * D_ + kb + scol);
        }
        __syncthreads();  // previous iter's fragment reads done
#pragma unroll
        for (int p = 0; p < 8; p++) {
            int r = srow + p * 16;
            *reinterpret_cast<uint2*>((char*)Qs + swz(r, scol * 2)) = pack4(fq[p]);
            *reinterpret_cast<uint2*>((char*)Ks + swz(r, scol * 2)) = pack4(fk[p]);
        }
        __syncthreads();
#pragma unroll
        for (int ks = 0; ks < 2; ks++) {
            const int kby = ks * 64 + (lane >> 4) * 16;
            bf16x8 a[4], bb[4];
#pragma unroll
            for (int m = 0; m < 4; m++) {
                int r = wm * 64 + m * 16 + (lane & 15);
                a[m] = *reinterpret_cast<const bf16x8*>((const char*)Qs + swz(r, kby));
            }
#pragma unroll
            for (int n = 0; n < 4; n++) {
                int r = wn * 64 + n * 16 + (lane & 15);
                bb[n] = *reinterpret_cast<const bf16x8*>((const char*)Ks + swz(r, kby));
            }
#pragma unroll
            for (int m = 0; m < 4; m++)
#pragma unroll
                for (int n = 0; n < 4; n++)
                    acc[m][n] = __builtin_amdgcn_mfma_f32_16x16x32_bf16(a[m], bb[n], acc[m][n], 0, 0, 0);
        }
    }

    float* Wb = Wt + (size_t)b * S_ * S_;
#pragma unroll
    for (int m = 0; m < 4; m++) {
#pragma unroll
        for (int j = 0; j < 4; j++) {
            int row = mb + wm * 64 + m * 16 + (lane >> 4) * 4 + j;
            float* rp = Wb + (size_t)row * S_ + nb + wn * 64 + (lane & 15);
#pragma unroll
            for (int n = 0; n < 4; n++) rp[n * 16] = acc[m][n][j];
        }
    }
}

// ---------------------------------------------------------------------------
// K2: in-place row softmax of scores*INV_SCALE. One block (256 thr) per row,
// 16 f32/thread held in registers: read once, write once.
// ---------------------------------------------------------------------------
__global__ __launch_bounds__(256) void k_softmax(float* __restrict__ Wt) {
    const size_t row = blockIdx.x;
    float* p = Wt + row * S_;
    const int t = threadIdx.x;
    const int lane = t & 63, wv = t >> 6;
    __shared__ float red[4];

    float4 x[4];
#pragma unroll
    for (int j = 0; j < 4; j++)
        x[j] = *reinterpret_cast<const float4*>(p + t * 4 + j * 1024);

    float mx = -1e30f;
#pragma unroll
    for (int j = 0; j < 4; j++) {
        x[j].x *= INV_SCALE; x[j].y *= INV_SCALE;
        x[j].z *= INV_SCALE; x[j].w *= INV_SCALE;
        mx = fmaxf(mx, fmaxf(fmaxf(x[j].x, x[j].y), fmaxf(x[j].z, x[j].w)));
    }
#pragma unroll
    for (int o = 32; o; o >>= 1) mx = fmaxf(mx, __shfl_xor(mx, o, 64));
    if (lane == 0) red[wv] = mx;
    __syncthreads();
    mx = fmaxf(fmaxf(red[0], red[1]), fmaxf(red[2], red[3]));
    __syncthreads();  // red reuse

    float sum = 0.f;
#pragma unroll
    for (int j = 0; j < 4; j++) {
        x[j].x = __expf(x[j].x - mx); x[j].y = __expf(x[j].y - mx);
        x[j].z = __expf(x[j].z - mx); x[j].w = __expf(x[j].w - mx);
        sum += x[j].x + x[j].y + x[j].z + x[j].w;
    }
#pragma unroll
    for (int o = 32; o; o >>= 1) sum += __shfl_xor(sum, o, 64);
    if (lane == 0) red[wv] = sum;
    __syncthreads();
    sum = red[0] + red[1] + red[2] + red[3];
    const float r = 1.0f / sum;
#pragma unroll
    for (int j = 0; j < 4; j++) {
        x[j].x *= r; x[j].y *= r; x[j].z *= r; x[j].w *= r;
        *reinterpret_cast<float4*>(p + t * 4 + j * 1024) = x[j];
    }
}

// ---------------------------------------------------------------------------
// k_vt: V [b][4096][256] fp32  ->  Vt [b][256][4096] bf16 (workspace)
// 64x64 tiles through padded LDS; coalesced on both sides.
// ---------------------------------------------------------------------------
__global__ __launch_bounds__(256) void k_vt(const float* __restrict__ V,
                                            unsigned short* __restrict__ Vt) {
    __shared__ float tile[64][65];
    const int t = threadIdx.x;
    const int kb = blockIdx.x * 64;  // S dim
    const int nb = blockIdx.y * 64;  // D dim
    const int b = blockIdx.z;
    const float* Vb = V + (size_t)b * S_ * D_;
    {
        const int r = t >> 2, c4 = (t & 3) * 16;
#pragma unroll
        for (int j = 0; j < 4; j++) {
            float4 f = *reinterpret_cast<const float4*>(Vb + (size_t)(kb + r) * D_ + nb + c4 + j * 4);
            tile[r][c4 + j * 4 + 0] = f.x;
            tile[r][c4 + j * 4 + 1] = f.y;
            tile[r][c4 + j * 4 + 2] = f.z;
            tile[r][c4 + j * 4 + 3] = f.w;
        }
    }
    __syncthreads();
    {
        const int n = t >> 2, k4 = (t & 3) * 16;
        union { __bf16 h[16]; uint4 u[2]; } o;
#pragma unroll
        for (int j = 0; j < 16; j++) o.h[j] = (__bf16)tile[k4 + j][n];
        unsigned short* Ob = Vt + (size_t)b * D_ * S_ + (size_t)(nb + n) * S_ + kb + k4;
        *reinterpret_cast<uint4*>(Ob) = o.u[0];
        *reinterpret_cast<uint4*>(Ob + 8) = o.u[1];
    }
}

// ---------------------------------------------------------------------------
// K3: out = W . V   (M-tile 64, N=256 full so W is read exactly once, BK=64)
// 4 waves 1x4, each wave 64x64 (4x4 fragments).
// USE_VT=1: B staged from precomputed bf16 V^T (vector loads).
// USE_VT=0: fallback, in-block transpose of fp32 V via scalar column reads.
// ---------------------------------------------------------------------------
template <bool USE_VT>
__global__ __launch_bounds__(256) void k_pv(const float* __restrict__ Wt,
                                            const float* __restrict__ V,
                                            const unsigned short* __restrict__ Vtg,
                                            float* __restrict__ Out) {
    __shared__ alignas(16) unsigned short Ws[64 * 64];
    __shared__ alignas(16) unsigned short Vs[256 * 64];
    const int t = threadIdx.x, lane = t & 63, wv = t >> 6;
    const int mb = blockIdx.x * 64;
    const int b = blockIdx.y;
    const float* Wb = Wt + (size_t)b * S_ * S_;

    f32x4 acc[4][4];
#pragma unroll
    for (int i = 0; i < 4; i++)
#pragma unroll
        for (int j = 0; j < 4; j++) acc[i][j] = f32x4{0.f, 0.f, 0.f, 0.f};

    const int srow = t >> 4;        // 0..15
    const int scol = (t & 15) * 4;  // float col in 64-wide k slab

    for (int kb = 0; kb < S_; kb += 64) {
        __syncthreads();  // previous iter's fragment reads done
        // stage W tile (64 x 64 fp32 -> bf16)
#pragma unroll
        for (int p = 0; p < 4; p++) {
            int r = srow + p * 16;
            float4 fw = *reinterpret_cast<const float4*>(Wb + (size_t)(mb + r) * S_ + kb + scol);
            *reinterpret_cast<uint2*>((char*)Ws + swz(r, scol * 2)) = pack4(fw);
        }
        if (USE_VT) {
            // stage V^T tile: rows n=0..255, 128B each, vector 16B loads
            const unsigned short* Vtb = Vtg + (size_t)b * D_ * S_ + kb;
            const int chunk = (t & 7) * 8;  // bf16 elems
#pragma unroll
            for (int p = 0; p < 8; p++) {
                int row = (t >> 3) + p * 32;
                uint4 u = *reinterpret_cast<const uint4*>(Vtb + (size_t)row * S_ + chunk);
                *reinterpret_cast<uint4*>((char*)Vs + swz(row, chunk * 2)) = u;
            }
        } else {
            // in-block transpose: thread t owns column n=t of V
            const float* vp = V + (size_t)b * S_ * D_ + (size_t)kb * D_ + t;
#pragma unroll
            for (int c = 0; c < 8; c++) {
                float f[8];
#pragma unroll
                for (int j = 0; j < 8; j++) f[j] = vp[j * D_];
                vp += 8 * D_;
                union { __bf16 h[8]; uint4 u; } r;
#pragma unroll
                for (int j = 0; j < 8; j++) r.h[j] = (__bf16)f[j];
                *reinterpret_cast<uint4*>((char*)Vs + swz(t, c * 16)) = r.u;
            }
        }
        __syncthreads();
#pragma unroll
        for (int ks = 0; ks < 2; ks++) {
            const int kby = ks * 64 + (lane >> 4) * 16;
            bf16x8 a[4], bv[4];
#pragma unroll
            for (int m = 0; m < 4; m++)
                a[m] = *reinterpret_cast<const bf16x8*>((const char*)Ws + swz(m * 16 + (lane & 15), kby));
#pragma unroll
            for (int n = 0; n < 4; n++)
                bv[n] = *reinterpret_cast<const bf16x8*>((const char*)Vs + swz(wv * 64 + n * 16 + (lane & 15), kby));
#pragma unroll
            for (int m = 0; m < 4; m++)
#pragma unroll
                for (int n = 0; n < 4; n++)
                    acc[m][n] = __builtin_amdgcn_mfma_f32_16x16x32_bf16(a[m], bv[n], acc[m][n], 0, 0, 0);
        }
    }

    float* Ob = Out + (size_t)b * S_ * D_;
#pragma unroll
    for (int m = 0; m < 4; m++) {
#pragma unroll
        for (int j = 0; j < 4; j++) {
            int row = mb + m * 16 + (lane >> 4) * 4 + j;
            float* rp = Ob + (size_t)row * D_ + wv * 64 + (lane & 15);
#pragma unroll
            for (int n = 0; n < 4; n++) rp[n * 16] = acc[m][n][j];
        }
    }
}

extern "C" void kernel_launch(void* const* d_in, const int* in_sizes, int n_in,
                              void* d_out, int out_size, void* d_ws, size_t ws_size,
                              hipStream_t stream) {
    const float* Q = (const float*)d_in[0];
    const float* K = (const float*)d_in[1];
    const float* V = (const float*)d_in[2];
    float* out = (float*)d_out;                       // B*S*D fp32
    float* Wt  = out + (size_t)B_ * S_ * D_;          // B*S*S fp32 weights

    k_qk<<<dim3(S_ / 128, S_ / 128, B_), 256, 0, stream>>>(Q, K, Wt);
    k_softmax<<<B_ * S_, 256, 0, stream>>>(Wt);

    const size_t vt_bytes = (size_t)B_ * D_ * S_ * sizeof(unsigned short); // 8 MiB
    if (ws_size >= vt_bytes) {
        unsigned short* Vtg = (unsigned short*)d_ws;
        k_vt<<<dim3(S_ / 64, D_ / 64, B_), 256, 0, stream>>>(V, Vtg);
        k_pv<true><<<dim3(S_ / 64, B_), 256, 0, stream>>>(Wt, V, Vtg, out);
    } else {
        k_pv<false><<<dim3(S_ / 64, B_), 256, 0, stream>>>(Wt, V, nullptr, out);
    }
}